// Round 5
// baseline (4192.883 us; speedup 1.0000x reference)
//
#include <hip/hip_runtime.h>
#include <hip/hip_cooperative_groups.h>
#include <math.h>

namespace cg = cooperative_groups;

// SLIC superpixel segmentation — bit-faithful f32 reimplementation of the JAX ref
// (XLA CPU semantics). Numerics decisions, all aimed at exact label match:
//  - dot(feats, centers) replicates Eigen sgemm: sequential k=0..4 FMA chain.
//  - f_sq / c_sq: rounded squares, sequential adds, NO fma (fp contract off).
//  - d = (f_sq + c_sq) - 2*dot, three separately-rounded ops.
//  - strict-< argmin (first occurrence, == jnp.argmin).
//  - segment_sum: EXACT ascending-pixel-index sequential adds per cluster,
//    via stable counting sort (block hist -> prefix -> rank scatter).
// R5 perf changes (no arithmetic reordering; outputs bit-identical to R4):
//  - ONE cooperative kernel, grid.sync() between phases: removes ~350us of
//    launch gaps + small-kernel tails (42 dispatches -> 1).
//  - assign: 4 pixels/thread share one set of center LDS reads (assign was
//    LDS-pipe-bound at ~20us; now ~6us). Hist granularity stays 256-px
//    sub-tiles so the counting sort is unchanged.
//  - fallback to the R4 multi-kernel path if cooperative launch is refused.

#pragma clang fp contract(off)

#define BATCH 8
#define HH 224
#define WW 224
#define HWPIX (HH * WW)        // 50176
#define KSEG 100
#define NSUB 196               // 256-px sub-tiles per batch (= R4 NBLK)
#define NTILE 49               // 1024-px assign tiles per batch
#define NITER 10
#define UCHUNK 1024            // update LDS chunk: 5*(1024+1)*4B = 20.5KB
#define GRID_G 784             // co-resident blocks (<= 4 blocks/CU * 256 CU)

union SMem {
    struct { float c8[KSEG * 8]; int hist[4 * KSEG]; } a;  // assign
    int lab[256];                                          // scatter
    float ubuf[5][UCHUNK + 1];                             // update
    int pcnt[KSEG];                                        // prefix
};

__device__ __forceinline__ float get_ratio() {
    double S = sqrt((double)(HH * WW) / (double)KSEG);
    return (float)(10.0 / S);
}

// ---------------- fused phases ----------------

__device__ void init_phase(const float* __restrict__ img, float* __restrict__ centers) {
#pragma clang fp contract(off)
    if (blockIdx.x >= BATCH || threadIdx.x >= KSEG) return;
    int b = blockIdx.x, k = threadIdx.x;
    int i = k / 10, j = k % 10;
    int y = (int)floor(((i + 0.5) * (double)HH) / 10.0);
    int x = (int)floor(((j + 0.5) * (double)WW) / 10.0);
    float ratio = get_ratio();
    int n = y * WW + x;
    const float* p = img + ((size_t)b * HWPIX + n) * 3;
    float* c = centers + (b * KSEG + k) * 5;
    c[0] = (float)y * ratio;
    c[1] = (float)x * ratio;
    c[2] = p[0];
    c[3] = p[1];
    c[4] = p[2];
}

__device__ void assign_phase(SMem* sm, const float* __restrict__ img,
                             const float* __restrict__ centers, int* __restrict__ labels,
                             int* __restrict__ blockHist, float* __restrict__ outLab,
                             float* __restrict__ outMean, int mode) {
#pragma clang fp contract(off)
    int t = blockIdx.x;
    if (t >= BATCH * NTILE) return;          // idle blocks fall through to grid.sync
    int b = t / NTILE, tile = t % NTILE;
    int tid = threadIdx.x;

    for (int i = tid; i < KSEG * 5; i += 256) {
        int k = i / 5, f = i - 5 * k;
        sm->a.c8[k * 8 + f] = centers[(size_t)b * KSEG * 5 + i];
    }
    for (int i = tid; i < 4 * KSEG; i += 256) sm->a.hist[i] = 0;
    __syncthreads();
    if (tid < KSEG) {
        const float* ck = sm->a.c8 + tid * 8;
        float s = ck[0] * ck[0];             // XLA fused mul+reduce: no fma, seq adds
        s = s + ck[1] * ck[1];
        s = s + ck[2] * ck[2];
        s = s + ck[3] * ck[3];
        s = s + ck[4] * ck[4];
        sm->a.c8[tid * 8 + 5] = s;
    }
    __syncthreads();

    float ratio = get_ratio();
    int n0 = tile * 1024 + tid;              // 4 pixels: n0 + {0,256,512,768}
    float yf[4], xf[4], rr[4], gg[4], bb[4], fsq[4], dmin[4];
    int kb[4];
#pragma unroll
    for (int p = 0; p < 4; ++p) {
        int n = n0 + p * 256;
        int y = n / WW, x = n - y * WW;
        yf[p] = (float)y * ratio;
        xf[p] = (float)x * ratio;
        const float* pp = img + ((size_t)b * HWPIX + n) * 3;
        rr[p] = pp[0]; gg[p] = pp[1]; bb[p] = pp[2];
        float s = yf[p] * yf[p];             // no fma, seq adds (XLA reduce)
        s = s + xf[p] * xf[p];
        s = s + rr[p] * rr[p];
        s = s + gg[p] * gg[p];
        s = s + bb[p] * bb[p];
        fsq[p] = s;
        dmin[p] = INFINITY;
        kb[p] = 0;
    }

    for (int k = 0; k < KSEG; ++k) {
        float4 v0 = *reinterpret_cast<const float4*>(&sm->a.c8[k * 8]);  // ds_read_b128
        float c4v = sm->a.c8[k * 8 + 4];
        float csqv = sm->a.c8[k * 8 + 5];
#pragma unroll
        for (int p = 0; p < 4; ++p) {
            // Eigen sgemm micro-kernel: sequential FMA chain over contracted dim
            float dot = yf[p] * v0.x;        // == fma(yf, c0, 0)
            dot = __fmaf_rn(xf[p], v0.y, dot);
            dot = __fmaf_rn(rr[p], v0.z, dot);
            dot = __fmaf_rn(gg[p], v0.w, dot);
            dot = __fmaf_rn(bb[p], c4v, dot);
            float d = (fsq[p] + csqv) - 2.0f * dot;  // three separately-rounded ops
            if (d < dmin[p]) { dmin[p] = d; kb[p] = k; }  // strict < == jnp.argmin
        }
    }

#pragma unroll
    for (int p = 0; p < 4; ++p)
        labels[(size_t)b * HWPIX + n0 + p * 256] = kb[p];

    if (mode == 0) {
#pragma unroll
        for (int p = 0; p < 4; ++p) atomicAdd(&sm->a.hist[p * KSEG + kb[p]], 1);
        __syncthreads();
        for (int i = tid; i < 4 * KSEG; i += 256) {
            int part = i / KSEG, k = i - part * KSEG;
            blockHist[((size_t)b * NSUB + tile * 4 + part) * KSEG + k] = sm->a.hist[i];
        }
    } else {
#pragma unroll
        for (int p = 0; p < 4; ++p) {
            int n = n0 + p * 256;
            outLab[(size_t)b * HWPIX + n] = (float)kb[p];
            float* om = outMean + ((size_t)b * HWPIX + n) * 3;
            om[0] = sm->a.c8[kb[p] * 8 + 2];
            om[1] = sm->a.c8[kb[p] * 8 + 3];
            om[2] = sm->a.c8[kb[p] * 8 + 4];
        }
    }
    __syncthreads();
}

__device__ void prefix_phase(SMem* sm, const int* __restrict__ blockHist,
                             int* __restrict__ offsets, int* __restrict__ cbase,
                             int* __restrict__ ccount) {
    int b = blockIdx.x;
    if (b >= BATCH) return;
    int k = threadIdx.x;
    int run = 0;
    if (k < KSEG) {
        for (int blk = 0; blk < NSUB; ++blk) run += blockHist[((size_t)b * NSUB + blk) * KSEG + k];
        sm->pcnt[k] = run;
    }
    __syncthreads();
    if (k < KSEG) {
        int base = 0;
        for (int j = 0; j < k; ++j) base += sm->pcnt[j];
        int off = base;
        for (int blk = 0; blk < NSUB; ++blk) {
            size_t idx = ((size_t)b * NSUB + blk) * KSEG + k;
            int t = blockHist[idx];
            offsets[idx] = off;
            off += t;
        }
        cbase[b * KSEG + k] = base;
        ccount[b * KSEG + k] = run;
    }
    __syncthreads();
}

__device__ void scatter_phase(SMem* sm, const float* __restrict__ img,
                              const int* __restrict__ labels, const int* __restrict__ offsets,
                              float* __restrict__ sortedF) {
#pragma clang fp contract(off)
    float ratio = get_ratio();
    for (int s = blockIdx.x; s < BATCH * NSUB; s += GRID_G) {
        int b = s / NSUB, sub = s % NSUB;
        int tid = threadIdx.x;
        int n = sub * 256 + tid;
        int my = labels[(size_t)b * HWPIX + n];
        sm->lab[tid] = my;
        __syncthreads();
        int rank = 0;                        // stable rank within sub-tile
        for (int j = 0; j < tid; ++j) rank += (sm->lab[j] == my) ? 1 : 0;
        int pos = offsets[((size_t)b * NSUB + sub) * KSEG + my] + rank;
        int y = n / WW, x = n - y * WW;
        const float* p = img + ((size_t)b * HWPIX + n) * 3;
        float* sf = sortedF + (size_t)b * 5 * HWPIX;
        sf[0 * HWPIX + pos] = (float)y * ratio;
        sf[1 * HWPIX + pos] = (float)x * ratio;
        sf[2 * HWPIX + pos] = p[0];
        sf[3 * HWPIX + pos] = p[1];
        sf[4 * HWPIX + pos] = p[2];
        __syncthreads();                     // lab reused by next pass
    }
}

__device__ void update_phase(SMem* sm, const float* __restrict__ sortedF,
                             const int* __restrict__ cbase, const int* __restrict__ ccount,
                             float* __restrict__ centers) {
#pragma clang fp contract(off)
    for (int u = blockIdx.x; u < BATCH * KSEG; u += GRID_G) {
        int b = u / KSEG, k = u - b * KSEG;
        int tid = threadIdx.x;
        int base = cbase[b * KSEG + k], cnt = ccount[b * KSEG + k];
        const float* sf0 = sortedF + (size_t)b * 5 * HWPIX + base;
        float acc = 0.f;
        for (int c0 = 0; c0 < cnt; c0 += UCHUNK) {
            int m = min(UCHUNK, cnt - c0);
            for (int ch = 0; ch < 5; ++ch) {
                const float* src = sf0 + (size_t)ch * HWPIX + c0;
                for (int i = tid; i < m; i += 256) sm->ubuf[ch][i] = src[i];  // coalesced
            }
            __syncthreads();
            if (tid < 5) {
                float a = acc;
                const float* bp = sm->ubuf[tid];
                for (int i = 0; i < m; ++i) a = a + bp[i];  // exact ascending chain
                acc = a;
            }
            __syncthreads();
        }
        if (tid < 5 && cnt > 0)
            centers[(b * KSEG + k) * 5 + tid] = acc / (float)cnt;
        __syncthreads();
    }
}

__global__ void __launch_bounds__(256, 4)
k_fused(const float* __restrict__ img, float* __restrict__ outLab, float* __restrict__ outMean,
        float* __restrict__ centers, int* __restrict__ labels, int* __restrict__ blockHist,
        int* __restrict__ offsets, float* __restrict__ sortedF, int* __restrict__ cbase,
        int* __restrict__ ccount) {
    __shared__ SMem sm;
    cg::grid_group grid = cg::this_grid();
    init_phase(img, centers);
    grid.sync();
    for (int it = 0; it < NITER; ++it) {
        assign_phase(&sm, img, centers, labels, blockHist, outLab, outMean, 0);
        grid.sync();
        prefix_phase(&sm, blockHist, offsets, cbase, ccount);
        grid.sync();
        scatter_phase(&sm, img, labels, offsets, sortedF);
        grid.sync();
        update_phase(&sm, sortedF, cbase, ccount, centers);
        grid.sync();
    }
    assign_phase(&sm, img, centers, labels, blockHist, outLab, outMean, 1);
}

// ---------------- R4 fallback kernels (known-good) ----------------

__global__ void k_init(const float* __restrict__ img, float* __restrict__ centers) {
#pragma clang fp contract(off)
    int b = blockIdx.x;
    int k = threadIdx.x;
    if (k >= KSEG) return;
    int i = k / 10, j = k % 10;
    int y = (int)floor(((i + 0.5) * (double)HH) / 10.0);
    int x = (int)floor(((j + 0.5) * (double)WW) / 10.0);
    float ratio = get_ratio();
    int n = y * WW + x;
    const float* p = img + ((size_t)b * HWPIX + n) * 3;
    float* c = centers + (b * KSEG + k) * 5;
    c[0] = (float)y * ratio;
    c[1] = (float)x * ratio;
    c[2] = p[0];
    c[3] = p[1];
    c[4] = p[2];
}

__global__ void k_assign(const float* __restrict__ img, const float* __restrict__ centers,
                         int* __restrict__ labels, int* __restrict__ blockHist,
                         float* __restrict__ outLab, float* __restrict__ outMean, int mode) {
#pragma clang fp contract(off)
    __shared__ float c8[KSEG * 8];
    __shared__ int hist[KSEG];
    int b = blockIdx.y, bx = blockIdx.x, tid = threadIdx.x;
    for (int i = tid; i < KSEG * 5; i += 256) {
        int k = i / 5, f = i - 5 * k;
        c8[k * 8 + f] = centers[(size_t)b * KSEG * 5 + i];
    }
    if (tid < KSEG) hist[tid] = 0;
    __syncthreads();
    if (tid < KSEG) {
        const float* ck = c8 + tid * 8;
        float s = ck[0] * ck[0];
        s = s + ck[1] * ck[1];
        s = s + ck[2] * ck[2];
        s = s + ck[3] * ck[3];
        s = s + ck[4] * ck[4];
        c8[tid * 8 + 5] = s;
    }
    __syncthreads();
    int n = bx * 256 + tid;
    int y = n / WW, x = n - y * WW;
    float ratio = get_ratio();
    float yf = (float)y * ratio, xf = (float)x * ratio;
    const float* p = img + ((size_t)b * HWPIX + n) * 3;
    float r = p[0], g = p[1], bl = p[2];
    float fsq = yf * yf;
    fsq = fsq + xf * xf;
    fsq = fsq + r * r;
    fsq = fsq + g * g;
    fsq = fsq + bl * bl;
    float dmin = INFINITY;
    int kb = 0;
    for (int k = 0; k < KSEG; ++k) {
        float4 v0 = *reinterpret_cast<const float4*>(&c8[k * 8]);
        float c4v = c8[k * 8 + 4];
        float csqv = c8[k * 8 + 5];
        float dot = yf * v0.x;
        dot = __fmaf_rn(xf, v0.y, dot);
        dot = __fmaf_rn(r, v0.z, dot);
        dot = __fmaf_rn(g, v0.w, dot);
        dot = __fmaf_rn(bl, c4v, dot);
        float d = (fsq + csqv) - 2.0f * dot;
        if (d < dmin) { dmin = d; kb = k; }
    }
    labels[(size_t)b * HWPIX + n] = kb;
    if (mode == 0) {
        atomicAdd(&hist[kb], 1);
        __syncthreads();
        if (tid < KSEG) blockHist[((size_t)b * NSUB + bx) * KSEG + tid] = hist[tid];
    } else {
        outLab[(size_t)b * HWPIX + n] = (float)kb;
        float* om = outMean + ((size_t)b * HWPIX + n) * 3;
        om[0] = c8[kb * 8 + 2];
        om[1] = c8[kb * 8 + 3];
        om[2] = c8[kb * 8 + 4];
    }
}

__global__ void k_prefix(const int* __restrict__ blockHist, int* __restrict__ offsets,
                         int* __restrict__ cbase, int* __restrict__ ccount) {
    __shared__ int cnt[KSEG];
    int b = blockIdx.x, k = threadIdx.x;
    int run = 0;
    if (k < KSEG) {
        for (int blk = 0; blk < NSUB; ++blk) run += blockHist[((size_t)b * NSUB + blk) * KSEG + k];
        cnt[k] = run;
    }
    __syncthreads();
    if (k < KSEG) {
        int base = 0;
        for (int j = 0; j < k; ++j) base += cnt[j];
        int off = base;
        for (int blk = 0; blk < NSUB; ++blk) {
            size_t idx = ((size_t)b * NSUB + blk) * KSEG + k;
            int t = blockHist[idx];
            offsets[idx] = off;
            off += t;
        }
        cbase[b * KSEG + k] = base;
        ccount[b * KSEG + k] = run;
    }
}

__global__ void k_scatter(const float* __restrict__ img, const int* __restrict__ labels,
                          const int* __restrict__ offsets, float* __restrict__ sortedF) {
#pragma clang fp contract(off)
    __shared__ int lab[256];
    int b = blockIdx.y, bx = blockIdx.x, tid = threadIdx.x;
    int n = bx * 256 + tid;
    int my = labels[(size_t)b * HWPIX + n];
    lab[tid] = my;
    __syncthreads();
    int rank = 0;
    for (int j = 0; j < tid; ++j) rank += (lab[j] == my) ? 1 : 0;
    int pos = offsets[((size_t)b * NSUB + bx) * KSEG + my] + rank;
    int y = n / WW, x = n - y * WW;
    float ratio = get_ratio();
    const float* p = img + ((size_t)b * HWPIX + n) * 3;
    float* sf = sortedF + (size_t)b * 5 * HWPIX;
    sf[0 * HWPIX + pos] = (float)y * ratio;
    sf[1 * HWPIX + pos] = (float)x * ratio;
    sf[2 * HWPIX + pos] = p[0];
    sf[3 * HWPIX + pos] = p[1];
    sf[4 * HWPIX + pos] = p[2];
}

__global__ void k_update(const float* __restrict__ sortedF, const int* __restrict__ cbase,
                         const int* __restrict__ ccount, float* __restrict__ centers) {
#pragma clang fp contract(off)
    __shared__ float buf[5][2048 + 1];
    int k = blockIdx.x, b = blockIdx.y, tid = threadIdx.x;
    int base = cbase[b * KSEG + k], cnt = ccount[b * KSEG + k];
    const float* sf0 = sortedF + (size_t)b * 5 * HWPIX + base;
    float acc = 0.f;
    for (int c0 = 0; c0 < cnt; c0 += 2048) {
        int m = min(2048, cnt - c0);
        for (int ch = 0; ch < 5; ++ch) {
            const float* src = sf0 + (size_t)ch * HWPIX + c0;
            for (int i = tid; i < m; i += 256) buf[ch][i] = src[i];
        }
        __syncthreads();
        if (tid < 5) {
            float a = acc;
            const float* bp = buf[tid];
            for (int i = 0; i < m; ++i) a = a + bp[i];
            acc = a;
        }
        __syncthreads();
    }
    if (tid < 5 && cnt > 0) centers[(b * KSEG + k) * 5 + tid] = acc / (float)cnt;
}

// ---------------- launch ----------------

extern "C" void kernel_launch(void* const* d_in, const int* in_sizes, int n_in,
                              void* d_out, int out_size, void* d_ws, size_t ws_size,
                              hipStream_t stream) {
    const float* img = (const float*)d_in[0];
    float* outLab = (float*)d_out;                         // [8,224,224] labels as f32
    float* outMean = outLab + (size_t)BATCH * HWPIX;       // [8,224,224,3]

    char* ws = (char*)d_ws;
    float* centers = (float*)ws;  ws += (size_t)BATCH * KSEG * 5 * sizeof(float);
    int* labels    = (int*)ws;    ws += (size_t)BATCH * HWPIX * sizeof(int);
    int* blockHist = (int*)ws;    ws += (size_t)BATCH * NSUB * KSEG * sizeof(int);
    int* offsets   = (int*)ws;    ws += (size_t)BATCH * NSUB * KSEG * sizeof(int);
    float* sortedF = (float*)ws;  ws += (size_t)BATCH * 5 * HWPIX * sizeof(float);
    int* cbase     = (int*)ws;    ws += (size_t)BATCH * KSEG * sizeof(int);
    int* ccount    = (int*)ws;    ws += (size_t)BATCH * KSEG * sizeof(int);

    void* args[] = { (void*)&img, (void*)&outLab, (void*)&outMean, (void*)&centers,
                     (void*)&labels, (void*)&blockHist, (void*)&offsets, (void*)&sortedF,
                     (void*)&cbase, (void*)&ccount };
    hipError_t err = hipLaunchCooperativeKernel((const void*)k_fused, dim3(GRID_G), dim3(256),
                                                args, 0, stream);
    if (err != hipSuccess) {
        // deterministic fallback: known-good R4 multi-kernel path
        k_init<<<dim3(BATCH), 128, 0, stream>>>(img, centers);
        for (int it = 0; it < NITER; ++it) {
            k_assign<<<dim3(NSUB, BATCH), 256, 0, stream>>>(img, centers, labels, blockHist,
                                                            outLab, outMean, 0);
            k_prefix<<<dim3(BATCH), 128, 0, stream>>>(blockHist, offsets, cbase, ccount);
            k_scatter<<<dim3(NSUB, BATCH), 256, 0, stream>>>(img, labels, offsets, sortedF);
            k_update<<<dim3(KSEG, BATCH), 256, 0, stream>>>(sortedF, cbase, ccount, centers);
        }
        k_assign<<<dim3(NSUB, BATCH), 256, 0, stream>>>(img, centers, labels, blockHist,
                                                        outLab, outMean, 1);
    }
}

// Round 6
// 746.946 us; speedup vs baseline: 5.6134x; 5.6134x over previous
//
#include <hip/hip_runtime.h>
#include <math.h>

// SLIC superpixel segmentation — bit-faithful f32 reimplementation of the JAX ref
// (XLA CPU semantics). Numerics decisions, all aimed at exact label match:
//  - dot(feats, centers) replicates Eigen sgemm: sequential k=0..4 FMA chain.
//  - f_sq / c_sq: rounded squares, sequential adds, NO fma (fp contract off).
//  - d = (f_sq + c_sq) - 2*dot, three separately-rounded ops.
//  - strict-< argmin (first occurrence, == jnp.argmin).
//  - segment_sum: EXACT ascending-pixel-index sequential adds per cluster,
//    via stable counting sort (sub-tile hist -> prefix -> rank scatter).
// R6: cooperative fusion REVERTED (grid.sync on 784 blocks cost ~80us/sync:
// 4.3ms total, VALUBusy 5%, 40MB of spin FETCH). Multi-kernel graph replay
// (~2-4us/dispatch) is cheaper. Kept the two R5-validated phase wins:
//  - assign: 4 px/thread share one set of center LDS reads (LDS-pipe-bound
//    20us -> ~6us VALU-bound). Hist stays 256-px sub-tiles -> sort unchanged.
//  - scatter: wave-shuffle rank (64 __shfl steps + per-wave LDS hist, no
//    atomics) replaces the O(tid) serial LDS rank loop. Same pos, bit-identical.

#pragma clang fp contract(off)

#define BATCH 8
#define HH 224
#define WW 224
#define HWPIX (HH * WW)        // 50176
#define KSEG 100
#define NSUB 196               // 256-px sub-tiles per batch
#define NTILE 49               // 1024-px assign tiles per batch
#define NITER 10
#define UCHUNK 2048            // update LDS chunk: 5*(2048+1)*4B = 40.98KB

__device__ __forceinline__ float get_ratio() {
    double S = sqrt((double)(HH * WW) / (double)KSEG);
    return (float)(10.0 / S);
}

__global__ void k_init(const float* __restrict__ img, float* __restrict__ centers) {
#pragma clang fp contract(off)
    int b = blockIdx.x;
    int k = threadIdx.x;
    if (k >= KSEG) return;
    int i = k / 10, j = k % 10;
    int y = (int)floor(((i + 0.5) * (double)HH) / 10.0);
    int x = (int)floor(((j + 0.5) * (double)WW) / 10.0);
    float ratio = get_ratio();
    int n = y * WW + x;
    const float* p = img + ((size_t)b * HWPIX + n) * 3;
    float* c = centers + (b * KSEG + k) * 5;
    c[0] = (float)y * ratio;
    c[1] = (float)x * ratio;
    c[2] = p[0];
    c[3] = p[1];
    c[4] = p[2];
}

// 4 pixels per thread (n0 + {0,256,512,768}); hist kept per 256-px sub-tile.
// mode 0: labels + per-sub-tile histogram.  mode 1: final outputs.
__global__ void k_assign(const float* __restrict__ img, const float* __restrict__ centers,
                         int* __restrict__ labels, int* __restrict__ blockHist,
                         float* __restrict__ outLab, float* __restrict__ outMean, int mode) {
#pragma clang fp contract(off)
    __shared__ float c8[KSEG * 8];   // [c0,c1,c2,c3,c4,csq,pad,pad] per cluster
    __shared__ int hist[4 * KSEG];
    int b = blockIdx.y, tile = blockIdx.x, tid = threadIdx.x;

    for (int i = tid; i < KSEG * 5; i += 256) {
        int k = i / 5, f = i - 5 * k;
        c8[k * 8 + f] = centers[(size_t)b * KSEG * 5 + i];
    }
    for (int i = tid; i < 4 * KSEG; i += 256) hist[i] = 0;
    __syncthreads();
    if (tid < KSEG) {
        const float* ck = c8 + tid * 8;
        float s = ck[0] * ck[0];             // XLA fused mul+reduce: no fma, seq adds
        s = s + ck[1] * ck[1];
        s = s + ck[2] * ck[2];
        s = s + ck[3] * ck[3];
        s = s + ck[4] * ck[4];
        c8[tid * 8 + 5] = s;
    }
    __syncthreads();

    float ratio = get_ratio();
    int n0 = tile * 1024 + tid;
    float yf[4], xf[4], rr[4], gg[4], bb[4], fsq[4], dmin[4];
    int kb[4];
#pragma unroll
    for (int p = 0; p < 4; ++p) {
        int n = n0 + p * 256;
        int y = n / WW, x = n - y * WW;
        yf[p] = (float)y * ratio;
        xf[p] = (float)x * ratio;
        const float* pp = img + ((size_t)b * HWPIX + n) * 3;
        rr[p] = pp[0]; gg[p] = pp[1]; bb[p] = pp[2];
        float s = yf[p] * yf[p];             // no fma, seq adds (XLA reduce)
        s = s + xf[p] * xf[p];
        s = s + rr[p] * rr[p];
        s = s + gg[p] * gg[p];
        s = s + bb[p] * bb[p];
        fsq[p] = s;
        dmin[p] = INFINITY;
        kb[p] = 0;
    }

    for (int k = 0; k < KSEG; ++k) {
        float4 v0 = *reinterpret_cast<const float4*>(&c8[k * 8]);  // ds_read_b128
        float c4v = c8[k * 8 + 4];
        float csqv = c8[k * 8 + 5];
#pragma unroll
        for (int p = 0; p < 4; ++p) {
            // Eigen sgemm micro-kernel: sequential FMA chain over contracted dim
            float dot = yf[p] * v0.x;        // == fma(yf, c0, 0)
            dot = __fmaf_rn(xf[p], v0.y, dot);
            dot = __fmaf_rn(rr[p], v0.z, dot);
            dot = __fmaf_rn(gg[p], v0.w, dot);
            dot = __fmaf_rn(bb[p], c4v, dot);
            float d = (fsq[p] + csqv) - 2.0f * dot;   // three separately-rounded ops
            if (d < dmin[p]) { dmin[p] = d; kb[p] = k; }  // strict < == jnp.argmin
        }
    }

#pragma unroll
    for (int p = 0; p < 4; ++p)
        labels[(size_t)b * HWPIX + n0 + p * 256] = kb[p];

    if (mode == 0) {
#pragma unroll
        for (int p = 0; p < 4; ++p) atomicAdd(&hist[p * KSEG + kb[p]], 1);
        __syncthreads();
        for (int i = tid; i < 4 * KSEG; i += 256) {
            int part = i / KSEG, k = i - part * KSEG;
            blockHist[((size_t)b * NSUB + tile * 4 + part) * KSEG + k] = hist[i];
        }
    } else {
#pragma unroll
        for (int p = 0; p < 4; ++p) {
            int n = n0 + p * 256;
            outLab[(size_t)b * HWPIX + n] = (float)kb[p];
            float* om = outMean + ((size_t)b * HWPIX + n) * 3;
            om[0] = c8[kb[p] * 8 + 2];
            om[1] = c8[kb[p] * 8 + 3];
            om[2] = c8[kb[p] * 8 + 4];
        }
    }
}

__global__ void k_prefix(const int* __restrict__ blockHist, int* __restrict__ offsets,
                         int* __restrict__ cbase, int* __restrict__ ccount) {
    __shared__ int cnt[KSEG];
    int b = blockIdx.x, k = threadIdx.x;
    int run = 0;
    if (k < KSEG) {
        for (int blk = 0; blk < NSUB; ++blk) run += blockHist[((size_t)b * NSUB + blk) * KSEG + k];
        cnt[k] = run;
    }
    __syncthreads();
    if (k < KSEG) {
        int base = 0;
        for (int j = 0; j < k; ++j) base += cnt[j];
        int off = base;
        for (int blk = 0; blk < NSUB; ++blk) {
            size_t idx = ((size_t)b * NSUB + blk) * KSEG + k;
            int t = blockHist[idx];
            offsets[idx] = off;
            off += t;
        }
        cbase[b * KSEG + k] = base;
        ccount[b * KSEG + k] = run;
    }
}

// Stable scatter with wave-shuffle rank. pos identical to the serial version:
// rank = (#same-label lanes below me in my wave) + (same-label counts of
// earlier waves), tid == pixel order within the 256-px sub-tile.
__global__ void k_scatter(const float* __restrict__ img, const int* __restrict__ labels,
                          const int* __restrict__ offsets, float* __restrict__ sortedF) {
#pragma clang fp contract(off)
    __shared__ int whist[4 * KSEG];
    int b = blockIdx.y, sub = blockIdx.x, tid = threadIdx.x;
    int lane = tid & 63, w = tid >> 6;
    int n = sub * 256 + tid;
    int my = labels[(size_t)b * HWPIX + n];

    for (int i = tid; i < 4 * KSEG; i += 256) whist[i] = 0;
    __syncthreads();

    int rank_w = 0, cnt_w = 0;
    for (int l = 0; l < 64; ++l) {
        int ll = __shfl(my, l);
        if (ll == my) { cnt_w++; if (l < lane) rank_w++; }
    }
    if (rank_w == 0) whist[w * KSEG + my] = cnt_w;   // one writer per (wave,label)
    __syncthreads();
    int rank = rank_w;
    for (int w2 = 0; w2 < w; ++w2) rank += whist[w2 * KSEG + my];

    int pos = offsets[((size_t)b * NSUB + sub) * KSEG + my] + rank;
    int y = n / WW, x = n - y * WW;
    float ratio = get_ratio();
    const float* p = img + ((size_t)b * HWPIX + n) * 3;   // coalesced
    float* sf = sortedF + (size_t)b * 5 * HWPIX;
    sf[0 * HWPIX + pos] = (float)y * ratio;
    sf[1 * HWPIX + pos] = (float)x * ratio;
    sf[2 * HWPIX + pos] = p[0];
    sf[3 * HWPIX + pos] = p[1];
    sf[4 * HWPIX + pos] = p[2];
}

// One workgroup per (batch,cluster): 256 threads stage 5 x cnt sorted values
// into LDS (lane-coalesced), then 5 lanes do the EXACT ascending serial sums.
__global__ void k_update(const float* __restrict__ sortedF, const int* __restrict__ cbase,
                         const int* __restrict__ ccount, float* __restrict__ centers) {
#pragma clang fp contract(off)
    __shared__ float buf[5][UCHUNK + 1];     // +1: rows land in different banks
    int k = blockIdx.x, b = blockIdx.y, tid = threadIdx.x;
    int base = cbase[b * KSEG + k], cnt = ccount[b * KSEG + k];
    const float* sf0 = sortedF + (size_t)b * 5 * HWPIX + base;
    float acc = 0.f;
    for (int c0 = 0; c0 < cnt; c0 += UCHUNK) {
        int m = min(UCHUNK, cnt - c0);
        for (int ch = 0; ch < 5; ++ch) {
            const float* src = sf0 + (size_t)ch * HWPIX + c0;
            for (int i = tid; i < m; i += 256) buf[ch][i] = src[i];   // coalesced
        }
        __syncthreads();
        if (tid < 5) {
            float a = acc;
            const float* bp = buf[tid];
            for (int i = 0; i < m; ++i) a = a + bp[i];   // exact ascending chain
            acc = a;
        }
        __syncthreads();
    }
    if (tid < 5 && cnt > 0) {                // where(counts>0, sums/counts, old)
        centers[(b * KSEG + k) * 5 + tid] = acc / (float)cnt;
    }
}

extern "C" void kernel_launch(void* const* d_in, const int* in_sizes, int n_in,
                              void* d_out, int out_size, void* d_ws, size_t ws_size,
                              hipStream_t stream) {
    const float* img = (const float*)d_in[0];
    float* outLab = (float*)d_out;                         // [8,224,224] labels as f32
    float* outMean = outLab + (size_t)BATCH * HWPIX;       // [8,224,224,3]

    char* ws = (char*)d_ws;
    float* centers = (float*)ws;  ws += (size_t)BATCH * KSEG * 5 * sizeof(float);
    int* labels    = (int*)ws;    ws += (size_t)BATCH * HWPIX * sizeof(int);
    int* blockHist = (int*)ws;    ws += (size_t)BATCH * NSUB * KSEG * sizeof(int);
    int* offsets   = (int*)ws;    ws += (size_t)BATCH * NSUB * KSEG * sizeof(int);
    float* sortedF = (float*)ws;  ws += (size_t)BATCH * 5 * HWPIX * sizeof(float);
    int* cbase     = (int*)ws;    ws += (size_t)BATCH * KSEG * sizeof(int);
    int* ccount    = (int*)ws;    ws += (size_t)BATCH * KSEG * sizeof(int);

    k_init<<<dim3(BATCH), 128, 0, stream>>>(img, centers);
    for (int it = 0; it < NITER; ++it) {
        k_assign<<<dim3(NTILE, BATCH), 256, 0, stream>>>(img, centers, labels, blockHist,
                                                         outLab, outMean, 0);
        k_prefix<<<dim3(BATCH), 128, 0, stream>>>(blockHist, offsets, cbase, ccount);
        k_scatter<<<dim3(NSUB, BATCH), 256, 0, stream>>>(img, labels, offsets, sortedF);
        k_update<<<dim3(KSEG, BATCH), 256, 0, stream>>>(sortedF, cbase, ccount, centers);
    }
    k_assign<<<dim3(NTILE, BATCH), 256, 0, stream>>>(img, centers, labels, blockHist,
                                                     outLab, outMean, 1);
}